// Round 1
// baseline (302.171 us; speedup 1.0000x reference)
//
#include <hip/hip_runtime.h>
#include <math.h>

#define N_NODES 50000
#define N_EDGES 800000
#define IN_F 256
#define OUT_F 64
#define ALPHA 0.2f

__device__ __forceinline__ unsigned fmap(float x) {
    unsigned b = __float_as_uint(x);
    return (b & 0x80000000u) ? ~b : (b | 0x80000000u);
}
__device__ __forceinline__ float funmap(unsigned u) {
    return (u & 0x80000000u) ? __uint_as_float(u & 0x7fffffffu)
                             : __uint_as_float(~u);
}

// K1: Wh = leaky_relu(h @ W); e2 = Wh @ a[64:128]
// block = 256 threads, 64 rows/block, k-tiled (KT=64), 4 rows x 4 cols per thread
__global__ __launch_bounds__(256) void k1_gemm(
    const float* __restrict__ h, const float* __restrict__ W,
    const float* __restrict__ a, float* __restrict__ Wh,
    float* __restrict__ e2out) {
    __shared__ float hs[64 * 68];   // stride 68 to break bank conflicts
    __shared__ float wsm[64 * 64];

    const int tid = threadIdx.x;
    const int row0 = blockIdx.x * 64;
    const int cg = tid & 15;   // col group: cols cg*4 .. cg*4+3
    const int rg = tid >> 4;   // row group: rows rg*4 .. rg*4+3

    float acc[4][4] = {};

    for (int k0 = 0; k0 < IN_F; k0 += 64) {
        __syncthreads();
#pragma unroll
        for (int j = 0; j < 4; ++j) {
            int q = tid + j * 256;          // 0..1023
            int r = q >> 4;
            int c4 = (q & 15) * 4;
            int row = row0 + r;
            float4 v = make_float4(0.f, 0.f, 0.f, 0.f);
            if (row < N_NODES)
                v = *(const float4*)&h[(size_t)row * IN_F + k0 + c4];
            *(float4*)&hs[r * 68 + c4] = v;
        }
#pragma unroll
        for (int j = 0; j < 4; ++j) {
            int q = tid + j * 256;
            int r = q >> 4;
            int c4 = (q & 15) * 4;
            *(float4*)&wsm[r * 64 + c4] =
                *(const float4*)&W[(size_t)(k0 + r) * OUT_F + c4];
        }
        __syncthreads();

        for (int kk = 0; kk < 64; ++kk) {
            float4 wv = *(const float4*)&wsm[kk * 64 + cg * 4];
#pragma unroll
            for (int i = 0; i < 4; ++i) {
                float hv = hs[(rg * 4 + i) * 68 + kk];
                acc[i][0] += hv * wv.x;
                acc[i][1] += hv * wv.y;
                acc[i][2] += hv * wv.z;
                acc[i][3] += hv * wv.w;
            }
        }
    }

    float a2[4];
#pragma unroll
    for (int j = 0; j < 4; ++j) a2[j] = a[OUT_F + cg * 4 + j];

#pragma unroll
    for (int i = 0; i < 4; ++i) {
        int row = row0 + rg * 4 + i;
        float4 lr;
        float p2 = 0.f;
        {
            float v;
            v = acc[i][0]; v = v > 0.f ? v : ALPHA * v; lr.x = v; p2 += v * a2[0];
            v = acc[i][1]; v = v > 0.f ? v : ALPHA * v; lr.y = v; p2 += v * a2[1];
            v = acc[i][2]; v = v > 0.f ? v : ALPHA * v; lr.z = v; p2 += v * a2[2];
            v = acc[i][3]; v = v > 0.f ? v : ALPHA * v; lr.w = v; p2 += v * a2[3];
        }
        if (row < N_NODES)
            *(float4*)&Wh[(size_t)row * OUT_F + cg * 4] = lr;
        // reduce p2 across the 16 col-group lanes (xor within 16-lane group)
#pragma unroll
        for (int mask = 1; mask < 16; mask <<= 1)
            p2 += __shfl_xor(p2, mask, 64);
        if (cg == 0 && row < N_NODES) e2out[row] = p2;
    }
}

// K2: per-edge atomic max of e2[dst] into m[src] (monotone uint encoding)
__global__ __launch_bounds__(256) void k2_max(
    const int* __restrict__ ei, const float* __restrict__ e2,
    unsigned* __restrict__ m_u) {
    int e = blockIdx.x * blockDim.x + threadIdx.x;
    if (e >= N_EDGES) return;
    int s = ei[e];
    int d = ei[N_EDGES + e];
    atomicMax(m_u + s, fmap(e2[d]));
}

// K3: one wave per edge; lane = output feature.
// hacc[src] += exp(e2[dst]-m[src]) * Wh[dst]; denom[src] += exp(...)
__global__ __launch_bounds__(256) void k3_agg(
    const int* __restrict__ ei, const float* __restrict__ e2,
    const unsigned* __restrict__ m_u, const float* __restrict__ Wh,
    float* __restrict__ denom, float* __restrict__ hacc) {
    const int lane = threadIdx.x & 63;
    const int wave = (blockIdx.x * blockDim.x + threadIdx.x) >> 6;
    const int nwaves = (gridDim.x * blockDim.x) >> 6;
    for (int e = wave; e < N_EDGES; e += nwaves) {
        int s = __builtin_amdgcn_readfirstlane(ei[e]);
        int d = __builtin_amdgcn_readfirstlane(ei[N_EDGES + e]);
        float ee = __expf(e2[d] - funmap(m_u[s]));
        if (lane == 0) atomicAdd(denom + s, ee);
        float v = Wh[(size_t)d * OUT_F + lane];
        atomicAdd(hacc + (size_t)s * OUT_F + lane, ee * v);
    }
}

// K4: out = elu(hacc / denom), 0 for empty segments
__global__ __launch_bounds__(256) void k4_fin(
    const float* __restrict__ hacc, const float* __restrict__ denom,
    float* __restrict__ out) {
    int i = blockIdx.x * blockDim.x + threadIdx.x;
    if (i >= N_NODES * OUT_F) return;
    float dn = denom[i >> 6];
    float v = dn > 0.f ? hacc[i] / dn : 0.f;
    out[i] = v > 0.f ? v : expm1f(v);
}

extern "C" void kernel_launch(void* const* d_in, const int* in_sizes, int n_in,
                              void* d_out, int out_size, void* d_ws,
                              size_t ws_size, hipStream_t stream) {
    const float* h = (const float*)d_in[0];
    const int* ei = (const int*)d_in[1];
    const float* W = (const float*)d_in[2];
    const float* a = (const float*)d_in[3];
    float* out = (float*)d_out;

    float* ws = (float*)d_ws;
    float* Wh = ws;                              // 3,200,000 floats
    float* e2 = ws + 3200000;                    // 50,000
    unsigned* m_u = (unsigned*)(ws + 3250000);   // 50,000
    float* denom = ws + 3300000;                 // 50,000
    float* hacc = ws + 3350000;                  // 3,200,000

    // zero m (uint 0 < fmap(any float)), denom, hacc — contiguous region
    hipMemsetAsync(ws + 3250000, 0, (size_t)(50000 + 50000 + 3200000) * 4,
                   stream);

    k1_gemm<<<(N_NODES + 63) / 64, 256, 0, stream>>>(h, W, a, Wh, e2);
    k2_max<<<(N_EDGES + 255) / 256, 256, 0, stream>>>(ei, e2, m_u);
    k3_agg<<<2048, 256, 0, stream>>>(ei, e2, m_u, Wh, denom, hacc);
    k4_fin<<<(N_NODES * OUT_F + 255) / 256, 256, 0, stream>>>(hacc, denom, out);
}